// Round 1
// baseline (96.954 us; speedup 1.0000x reference)
//
#include <hip/hip_runtime.h>

// ConfusionAwareLoss: mean over B rows of
//   (max + log(sum exp(x - max)) - x[target]) * penalty[target, argmax]
// B=131072, C=1000 fp32. Memory-bound: one 524 MB streaming read.

#define NCLASS   1000
#define NC4      250      // float4 per row (1000/4)
#define BLK      256      // 4 waves per block
#define WPB      4
#define NBLOCKS  2048     // 8192 waves, 16 rows/wave

__global__ __launch_bounds__(BLK) void cal_rows(
    const float* __restrict__ outputs,
    const int*   __restrict__ targets,
    const float* __restrict__ penalty,
    float* __restrict__ partials,
    int B)
{
    const int lane  = threadIdx.x & 63;
    const int widx  = threadIdx.x >> 6;
    const int gwave = blockIdx.x * WPB + widx;
    const int nwave = gridDim.x * WPB;

    float acc = 0.0f;

    for (int row = gwave; row < B; row += nwave) {
        const float4* rp = reinterpret_cast<const float4*>(outputs + (size_t)row * NCLASS);
        const float NEG = -__builtin_inff();

        // whole row in registers: 4 x float4 per lane, coalesced 16B/lane
        float4 v0 = rp[lane];
        float4 v1 = rp[lane + 64];
        float4 v2 = rp[lane + 128];
        float4 v3;
        const int c3 = lane + 192;
        if (c3 < NC4) v3 = rp[c3];
        else { v3.x = NEG; v3.y = NEG; v3.z = NEG; v3.w = NEG; }

        // per-lane max + argmax (first occurrence: strictly-greater over
        // ascending column order within the lane)
        float mval = v0.x; int midx = 4 * lane;
        #define UPD(val, col) do { if ((val) > mval) { mval = (val); midx = (col); } } while (0)
        UPD(v0.y, 4*lane + 1); UPD(v0.z, 4*lane + 2); UPD(v0.w, 4*lane + 3);
        { int b = 4*(lane +  64); UPD(v1.x, b); UPD(v1.y, b+1); UPD(v1.z, b+2); UPD(v1.w, b+3); }
        { int b = 4*(lane + 128); UPD(v2.x, b); UPD(v2.y, b+1); UPD(v2.z, b+2); UPD(v2.w, b+3); }
        { int b = 4*(lane + 192); UPD(v3.x, b); UPD(v3.y, b+1); UPD(v3.z, b+2); UPD(v3.w, b+3); }
        #undef UPD

        // 64-lane butterfly (max, argmax); smaller index wins ties
        #pragma unroll
        for (int off = 32; off > 0; off >>= 1) {
            float ov = __shfl_xor(mval, off, 64);
            int   oi = __shfl_xor(midx, off, 64);
            if (ov > mval || (ov == mval && oi < midx)) { mval = ov; midx = oi; }
        }

        // sum exp(x - max); pad lanes contribute exp(-inf) = 0
        float s;
        s  = __expf(v0.x - mval) + __expf(v0.y - mval) + __expf(v0.z - mval) + __expf(v0.w - mval);
        s += __expf(v1.x - mval) + __expf(v1.y - mval) + __expf(v1.z - mval) + __expf(v1.w - mval);
        s += __expf(v2.x - mval) + __expf(v2.y - mval) + __expf(v2.z - mval) + __expf(v2.w - mval);
        s += __expf(v3.x - mval) + __expf(v3.y - mval) + __expf(v3.z - mval) + __expf(v3.w - mval);
        #pragma unroll
        for (int off = 32; off > 0; off >>= 1) s += __shfl_xor(s, off, 64);

        // target logit: uniform (jt, et) select chain — no runtime array index
        const int t   = targets[row];
        const int c4t = t >> 2;
        const int lt  = c4t & 63;
        const int jt  = c4t >> 6;
        const int et  = t & 3;
        float4 vv = (jt == 0) ? v0 : (jt == 1) ? v1 : (jt == 2) ? v2 : v3;
        float  xe = (et == 0) ? vv.x : (et == 1) ? vv.y : (et == 2) ? vv.z : vv.w;
        float tval = __shfl(xe, lt, 64);

        if (lane == 0) {
            float pen = penalty[(size_t)t * NCLASS + midx];
            acc += (mval + __logf(s) - tval) * pen;
        }
    }

    __shared__ float wsum[WPB];
    if (lane == 0) wsum[widx] = acc;
    __syncthreads();
    if (threadIdx.x == 0)
        partials[blockIdx.x] = wsum[0] + wsum[1] + wsum[2] + wsum[3];
}

__global__ __launch_bounds__(256) void cal_final(
    const float* __restrict__ partials, int n, float* __restrict__ out, float invB)
{
    float s = 0.0f;
    for (int i = threadIdx.x; i < n; i += 256) s += partials[i];
    #pragma unroll
    for (int off = 32; off > 0; off >>= 1) s += __shfl_xor(s, off, 64);
    __shared__ float wsum[4];
    const int widx = threadIdx.x >> 6;
    const int lane = threadIdx.x & 63;
    if (lane == 0) wsum[widx] = s;
    __syncthreads();
    if (threadIdx.x == 0) out[0] = (wsum[0] + wsum[1] + wsum[2] + wsum[3]) * invB;
}

extern "C" void kernel_launch(void* const* d_in, const int* in_sizes, int n_in,
                              void* d_out, int out_size, void* d_ws, size_t ws_size,
                              hipStream_t stream)
{
    const float* outputs = (const float*)d_in[0];
    const int*   targets = (const int*)d_in[1];
    const float* penalty = (const float*)d_in[2];
    float* out = (float*)d_out;
    const int B = in_sizes[1];

    float* partials = (float*)d_ws;
    int grid = NBLOCKS;
    if (ws_size < (size_t)grid * sizeof(float))
        grid = (int)(ws_size / sizeof(float));   // defensive; expect ws >= 8 KB

    cal_rows<<<grid, BLK, 0, stream>>>(outputs, targets, penalty, partials, B);
    cal_final<<<1, 256, 0, stream>>>(partials, grid, out, 1.0f / (float)B);
}